// Round 4
// baseline (575.184 us; speedup 1.0000x reference)
//
#include <hip/hip_runtime.h>

#define NROWS 32768
#define DIM 256
#define KCODES 1024
#define DECAYF 0.99f
#define EPSF 1e-5f

// ---------------- workspace layout (bytes) ----------------
// idx:       int[32768]     @ 0         (131072)
// counts:    int[1024]      @ 131072    (4096)
// embeds:    float[262144]  @ 135168    (1048576)
// loss_part: float[8192]    @ 1183744   (32768)
// enorm:     float[1024]    @ 1216512   (4096)
// total:     float[1]       @ 1220608   (4)

// ---------------- output layout (floats) ----------------
// quantized_st:      [0, 8388608)
// token_ids:         [8388608, 8421376)
// commitment_loss:   [8421376, 8421377)
// new_embedding:     [8421377, 8683521)
// new_cluster_size:  [8683521, 8684545)
// new_embedding_avg: [8684545, 8946689)

__global__ __launch_bounds__(256) void k_enorm(const float* __restrict__ e,
                                               float* __restrict__ enorm) {
    int w = threadIdx.x >> 6, lane = threadIdx.x & 63;
    int c = blockIdx.x * 4 + w;
    const float4 v = *(const float4*)&e[(size_t)c * DIM + lane * 4];
    float s = v.x * v.x + v.y * v.y + v.z * v.z + v.w * v.w;
#pragma unroll
    for (int m = 32; m; m >>= 1) s += __shfl_xor(s, m, 64);
    if (lane == 0) enorm[c] = s;
}

// Fused distance + argmin. Block = 256 threads (16 tx x 16 ty).
// Tile: 64 rows x 64 codes per K-step; e-tile in LDS (64KB, XOR-swizzled),
// x streamed from global (L2-resident per block). 4x4 register blocking.
__global__ __launch_bounds__(256, 2) void k_dist(const float* __restrict__ x,
                                                 const float* __restrict__ e,
                                                 const float* __restrict__ enorm,
                                                 int* __restrict__ out_idx) {
    __shared__ float es[64 * 256];  // exactly 64 KB

    const int t = threadIdx.x;
    const int tx = t & 15, ty = t >> 4;
    const int lane = t & 63, w = t >> 6;
    const int row0 = blockIdx.x * 64;

    float best[4];
    int bestidx[4];
#pragma unroll
    for (int i = 0; i < 4; ++i) { best[i] = 3.0e38f; bestidx[i] = 0; }

    const float* xbase[4];
#pragma unroll
    for (int i = 0; i < 4; ++i)
        xbase[i] = x + (size_t)(row0 + ty + 16 * i) * DIM;

    const int txs = tx & 7;  // swizzle constant for this thread's e-rows

    for (int kt = 0; kt < 16; ++kt) {
        __syncthreads();
        // stage e tile: wave w stages codes w*16 .. w*16+15
#pragma unroll
        for (int r = 0; r < 16; ++r) {
            int c = w * 16 + r;
            float4 v = *(const float4*)&e[(size_t)(kt * 64 + c) * DIM + lane * 4];
            *(float4*)&es[c * DIM + ((lane ^ (c & 7)) << 2)] = v;
        }
        __syncthreads();

        float acc[4][4];
#pragma unroll
        for (int i = 0; i < 4; ++i)
#pragma unroll
            for (int j = 0; j < 4; ++j) acc[i][j] = 0.0f;

#pragma unroll 4
        for (int d4 = 0; d4 < 64; ++d4) {
            float4 xv[4], ev[4];
#pragma unroll
            for (int i = 0; i < 4; ++i)
                xv[i] = *(const float4*)(xbase[i] + (d4 << 2));
#pragma unroll
            for (int j = 0; j < 4; ++j) {
                int c = tx + 16 * j;
                ev[j] = *(const float4*)&es[c * DIM + ((d4 ^ txs) << 2)];
            }
#pragma unroll
            for (int i = 0; i < 4; ++i)
#pragma unroll
                for (int j = 0; j < 4; ++j)
                    acc[i][j] += xv[i].x * ev[j].x + xv[i].y * ev[j].y +
                                 xv[i].z * ev[j].z + xv[i].w * ev[j].w;
        }

#pragma unroll
        for (int j = 0; j < 4; ++j) {
            int c = kt * 64 + tx + 16 * j;
            float en = enorm[c];
#pragma unroll
            for (int i = 0; i < 4; ++i) {
                float dist = en - 2.0f * acc[i][j];
                if (dist < best[i] || (dist == best[i] && c < bestidx[i])) {
                    best[i] = dist;
                    bestidx[i] = c;
                }
            }
        }
    }

    // reduce min across the 16 tx-lanes sharing each row
#pragma unroll
    for (int i = 0; i < 4; ++i) {
        float v = best[i];
        int bi = bestidx[i];
#pragma unroll
        for (int m = 1; m < 16; m <<= 1) {
            float v2 = __shfl_xor(v, m, 64);
            int b2 = __shfl_xor(bi, m, 64);
            if (v2 < v || (v2 == v && b2 < bi)) { v = v2; bi = b2; }
        }
        if (tx == 0) out_idx[row0 + ty + 16 * i] = bi;
    }
}

// gather quantized rows, straight-through output, loss partials, EMA scatter
__global__ __launch_bounds__(256) void k_scatter(const float* __restrict__ x,
                                                 const float* __restrict__ e,
                                                 const int* __restrict__ idx,
                                                 float* __restrict__ out_q,
                                                 float* __restrict__ out_tok,
                                                 int* __restrict__ counts,
                                                 float* __restrict__ embeds,
                                                 float* __restrict__ loss_part) {
    __shared__ float lred[4];
    int w = threadIdx.x >> 6, lane = threadIdx.x & 63;
    int n = blockIdx.x * 4 + w;
    int k = idx[n];

    size_t xo = (size_t)n * DIM + lane * 4;
    size_t eo = (size_t)k * DIM + lane * 4;
    const float4 xv = *(const float4*)&x[xo];
    const float4 ev = *(const float4*)&e[eo];

    float4 q;  // straight-through: x + (q - x), same rounding as reference
    q.x = xv.x + (ev.x - xv.x);
    q.y = xv.y + (ev.y - xv.y);
    q.z = xv.z + (ev.z - xv.z);
    q.w = xv.w + (ev.w - xv.w);
    *(float4*)&out_q[xo] = q;

    float dx = xv.x - ev.x, dy = xv.y - ev.y, dz = xv.z - ev.z, dw = xv.w - ev.w;
    float ls = dx * dx + dy * dy + dz * dz + dw * dw;
#pragma unroll
    for (int m = 32; m; m >>= 1) ls += __shfl_xor(ls, m, 64);
    if (lane == 0) {
        lred[w] = ls;
        atomicAdd(&counts[k], 1);
        out_tok[n] = (float)k;
    }

    atomicAdd(&embeds[eo + 0], xv.x);
    atomicAdd(&embeds[eo + 1], xv.y);
    atomicAdd(&embeds[eo + 2], xv.z);
    atomicAdd(&embeds[eo + 3], xv.w);

    __syncthreads();
    if (threadIdx.x == 0)
        loss_part[blockIdx.x] = lred[0] + lred[1] + lred[2] + lred[3];
}

__global__ __launch_bounds__(1024) void k_stats(const float* __restrict__ cs,
                                                const int* __restrict__ counts,
                                                const float* __restrict__ loss_part,
                                                float* __restrict__ out_loss,
                                                float* __restrict__ out_ncs,
                                                float* __restrict__ ws_total) {
    __shared__ float red[1024];
    int t = threadIdx.x;

    float ls = 0.0f;
    for (int i = t; i < 8192; i += 1024) ls += loss_part[i];
    red[t] = ls;
    __syncthreads();
    for (int s = 512; s; s >>= 1) {
        if (t < s) red[t] += red[t + s];
        __syncthreads();
    }
    if (t == 0) out_loss[0] = red[0] / 8388608.0f;
    __syncthreads();

    float ncs = cs[t] * DECAYF + (1.0f - DECAYF) * (float)counts[t];
    out_ncs[t] = ncs;
    red[t] = ncs;
    __syncthreads();
    for (int s = 512; s; s >>= 1) {
        if (t < s) red[t] += red[t + s];
        __syncthreads();
    }
    if (t == 0) ws_total[0] = red[0];
}

__global__ __launch_bounds__(64) void k_final(const float* __restrict__ avg,
                                              const float* __restrict__ embeds,
                                              const float* __restrict__ out_ncs,
                                              const float* __restrict__ ws_total,
                                              float* __restrict__ out_emb,
                                              float* __restrict__ out_avg) {
    int k = blockIdx.x, lane = threadIdx.x;
    float total = ws_total[0];
    float ncs = out_ncs[k];
    float normalized = (ncs + EPSF) / (total + (float)KCODES * EPSF) * total;

    size_t o = (size_t)k * DIM + lane * 4;
    float4 av = *(const float4*)&avg[o];
    float4 em = *(const float4*)&embeds[o];
    float4 na, ne;
    na.x = av.x * DECAYF + (1.0f - DECAYF) * em.x;
    na.y = av.y * DECAYF + (1.0f - DECAYF) * em.y;
    na.z = av.z * DECAYF + (1.0f - DECAYF) * em.z;
    na.w = av.w * DECAYF + (1.0f - DECAYF) * em.w;
    ne.x = na.x / normalized;
    ne.y = na.y / normalized;
    ne.z = na.z / normalized;
    ne.w = na.w / normalized;
    *(float4*)&out_avg[o] = na;
    *(float4*)&out_emb[o] = ne;
}

extern "C" void kernel_launch(void* const* d_in, const int* in_sizes, int n_in,
                              void* d_out, int out_size, void* d_ws, size_t ws_size,
                              hipStream_t stream) {
    const float* x   = (const float*)d_in[0];  // inputs [128,16,16,256]
    const float* emb = (const float*)d_in[1];  // embedding [1024,256]
    const float* cs  = (const float*)d_in[2];  // cluster_size [1024]
    const float* avg = (const float*)d_in[3];  // embedding_avg [1024,256]

    float* out      = (float*)d_out;
    float* out_q    = out;
    float* out_tok  = out + 8388608;
    float* out_loss = out + 8421376;
    float* out_emb  = out + 8421377;
    float* out_ncs  = out + 8683521;
    float* out_avg  = out + 8684545;

    char* ws         = (char*)d_ws;
    int* idx         = (int*)ws;
    int* counts      = (int*)(ws + 131072);
    float* embeds    = (float*)(ws + 135168);
    float* loss_part = (float*)(ws + 1183744);
    float* enorm     = (float*)(ws + 1216512);
    float* ws_total  = (float*)(ws + 1220608);

    // zero the scatter accumulators (counts + embeds); everything else is
    // fully overwritten every call
    hipMemsetAsync(ws + 131072, 0, 4096 + 1048576, stream);

    k_enorm<<<KCODES / 4, 256, 0, stream>>>(emb, enorm);
    k_dist<<<NROWS / 64, 256, 0, stream>>>(x, emb, enorm, idx);
    k_scatter<<<NROWS / 4, 256, 0, stream>>>(x, emb, idx, out_q, out_tok,
                                             counts, embeds, loss_part);
    k_stats<<<1, 1024, 0, stream>>>(cs, counts, loss_part, out_loss, out_ncs,
                                    ws_total);
    k_final<<<KCODES, 64, 0, stream>>>(avg, embeds, out_ncs, ws_total, out_emb,
                                       out_avg);
}